// Round 1
// 147.060 us; speedup vs baseline: 1.0161x; 1.0161x over previous
//
#include <hip/hip_runtime.h>

#define OD 26
#define OH 122
#define OW 122
#define GS (128*128)
#define NOUT (OD*OH*OW)

// Guide LDS tile for an 8x8x4 voxel block: needs 14 x 14 x 10 floats.
// TLX padded 14 -> 20: lane address (ty*20 + tx) mod 32 hits every bank
// exactly twice (2-way aliasing is free on CDNA4), so all ds_read_b32 in the
// hot loop are bank-conflict-free. 20*14*10 = 2800 floats = 11.2 KB.
#define TLX 20
#define TLY 14
#define TLZ 10
#define TLSLICE (TLX*TLY)      // 280
#define TLN (TLSLICE*TLZ)      // 2800

// Stage 0: domain kernel dk[27] — voxel-independent, computed once.
__global__ void compute_dk_kernel(const float* __restrict__ dn,
                                  const float* __restrict__ dw0, const float* __restrict__ db0,
                                  const float* __restrict__ dw1, const float* __restrict__ db1,
                                  float* __restrict__ dk_out) {
    __shared__ float d0[125];
    int t = threadIdx.x;
    if (t < 125) {
        int tz = t / 25, ty = (t / 5) % 5, tx = t % 5;
        float acc = db0[0];
        #pragma unroll
        for (int kz = 0; kz < 3; ++kz)
            #pragma unroll
            for (int ky = 0; ky < 3; ++ky)
                #pragma unroll
                for (int kx = 0; kx < 3; ++kx)
                    acc += dw0[kz*9 + ky*3 + kx] *
                           dn[(1+tz+kz)*81 + (1+ty+ky)*9 + (1+tx+kx)];
        d0[t] = fmaxf(acc, 0.0f);
    }
    __syncthreads();
    if (t < 27) {
        int rz = t / 9, ry = (t / 3) % 3, rx = t % 3;
        float acc = db1[0];
        #pragma unroll
        for (int kz = 0; kz < 3; ++kz)
            #pragma unroll
            for (int ky = 0; ky < 3; ++ky)
                #pragma unroll
                for (int kx = 0; kx < 3; ++kx)
                    acc += dw1[kz*9 + ky*3 + kx] * d0[(rz+kz)*25 + (ry+ky)*5 + (rx+kx)];
        dk_out[t] = fmaxf(acc, 0.0f);
    }
}

// Block = 8x8x4 voxel tile (256 threads). Guide tile staged in LDS.
//
// R5 restructure: the full-t0[125] version allocated 88 arch VGPRs and pushed
// the rest of the live set into AGPRs (unified file) -> v_accvgpr copy traffic
// (~1.9x VALU inflation) + 2-waves/SIMD occupancy cap. Here conv1 is computed
// ONE z-slice at a time (t0s[25]); each finished slice is immediately drained
// into the rk[27] accumulators (the conv2 taps with rz = tz1 - kz2), so peak
// live state is ~110 regs. Guide rows are re-read per slice (735 vs 343
// ds_reads) — cheap vs ~4.1k FMAs/thread.
//
// The asm volatile memory clobber between slices is REQUIRED: without it LLVM
// CSEs the repeated ds_reads across slices, rebuilding the full-tile live
// range and re-triggering the AGPR/scratch failure (R3's failure mode).
// __launch_bounds__(256, 3) caps VGPRs at ~168: comfortably above the actual
// pressure (no scratch spill — R2's failure mode), while guaranteeing
// 3 waves/SIMD. Do not raise the min-waves arg past 4.
__global__ __launch_bounds__(256, 3) void jbf_main_kernel(
        const float* __restrict__ x, const float* __restrict__ guide,
        const float* __restrict__ rw0p, const float* __restrict__ rb0p,
        const float* __restrict__ rw1p, const float* __restrict__ rb1p,
        const float* __restrict__ dkp, float* __restrict__ out) {
    __shared__ float gl[TLN];

    const int xb = blockIdx.x * 8;
    const int yb = blockIdx.y * 8;
    const int zb = blockIdx.z * 4;

    // Cooperative guide staging, coords clamped (edge tiles read dup rows;
    // in-range voxels only consume in-bounds neighbors, so values are exact.
    // Pad columns gx>=14 are never read; clamped loads keep them in-bounds).
    for (int i = threadIdx.x; i < TLN; i += 256) {
        const int gx = i % TLX;
        const int gy = (i / TLX) % TLY;
        const int gz = i / TLSLICE;
        const int sx = min(xb + gx, 127);
        const int sy = min(yb + gy, 127);
        const int sz = min(zb + gz, 31);
        gl[i] = guide[sz*GS + sy*128 + sx];
    }
    __syncthreads();

    const int tx = threadIdx.x & 7;
    const int ty = (threadIdx.x >> 3) & 7;
    const int tz = threadIdx.x >> 6;
    const int x0 = xb + tx;
    const int y0 = yb + ty;
    const int z0 = zb + tz;
    if (x0 >= OW || y0 >= OH || z0 >= OD) return;

    // Wave-uniform weights — loaded once, live in regs across the slice loop
    // (SSA values survive the memory clobbers; only LDS loads are re-issued).
    float rw0[27], rw1[27];
    #pragma unroll
    for (int i = 0; i < 27; ++i) { rw0[i] = rw0p[i]; rw1[i] = rw1p[i]; }
    const float rb0 = rb0p[0], rb1 = rb1p[0];

    // Per-thread LDS base: all inner reads are base + compile-time offset.
    const float* glb = &gl[tz*TLSLICE + ty*TLX + tx];
    const float gc = glb[3*TLSLICE + 3*TLX + 3];

    // conv2 accumulators (bias added once here; slice contributions add in).
    float rk[27];
    #pragma unroll
    for (int i = 0; i < 27; ++i) rk[i] = rb1;

    #pragma unroll
    for (int tz1 = 0; tz1 < 5; ++tz1) {
        // conv1, z-slice tz1: t0s(ty1,txx) = relu(rb0 + sum_k rw0(k)*|g - gc|)
        float t0s[25];
        #pragma unroll
        for (int i = 0; i < 25; ++i) t0s[i] = rb0;

        #pragma unroll
        for (int kz = 0; kz < 3; ++kz) {
            const int gz = tz1 + kz;
            #pragma unroll
            for (int gy = 0; gy < 7; ++gy) {
                float s[7];
                #pragma unroll
                for (int j = 0; j < 7; ++j)
                    s[j] = glb[gz*TLSLICE + gy*TLX + j] - gc;  // ds_read imm offset
                #pragma unroll
                for (int ky = 0; ky < 3; ++ky) {
                    const int ty1 = gy - ky;
                    if (ty1 < 0 || ty1 > 4) continue;          // folds at compile time
                    #pragma unroll
                    for (int txx = 0; txx < 5; ++txx)
                        #pragma unroll
                        for (int kx = 0; kx < 3; ++kx)
                            t0s[ty1*5 + txx] =
                                fmaf(rw0[kz*9 + ky*3 + kx], fabsf(s[txx + kx]),
                                     t0s[ty1*5 + txx]);
                }
            }
        }
        #pragma unroll
        for (int i = 0; i < 25; ++i) t0s[i] = fmaxf(t0s[i], 0.0f);

        // Drain slice into conv2 accumulators: rk(rz,·,·) gets the kz2 = tz1-rz tap.
        #pragma unroll
        for (int kz2 = 0; kz2 < 3; ++kz2) {
            const int rz = tz1 - kz2;
            if (rz < 0 || rz > 2) continue;                    // folds at compile time
            #pragma unroll
            for (int ry = 0; ry < 3; ++ry)
                #pragma unroll
                for (int rx = 0; rx < 3; ++rx) {
                    #pragma unroll
                    for (int ky2 = 0; ky2 < 3; ++ky2)
                        #pragma unroll
                        for (int kx2 = 0; kx2 < 3; ++kx2)
                            rk[rz*9 + ry*3 + rx] =
                                fmaf(rw1[kz2*9 + ky2*3 + kx2],
                                     t0s[(ry+ky2)*5 + (rx+kx2)],
                                     rk[rz*9 + ry*3 + rx]);
                }
        }

        // Block LDS-load CSE across slices — keeps per-slice pressure bounded.
        asm volatile("" ::: "memory");
    }

    // Epilogue: relu(rk) * dk weighting + normalized reduction.
    float num = 0.0f, den = 0.0f;
    const float* xbp = x + (z0+2)*GS + (y0+2)*128 + (x0+2);
    #pragma unroll
    for (int rz = 0; rz < 3; ++rz)
        #pragma unroll
        for (int ry = 0; ry < 3; ++ry)
            #pragma unroll
            for (int rx = 0; rx < 3; ++rx) {
                const float w = dkp[rz*9 + ry*3 + rx]
                              * fmaxf(rk[rz*9 + ry*3 + rx], 0.0f) + 1e-10f;
                den += w;
                num = fmaf(w, xbp[rz*GS + ry*128 + rx], num);
            }

    out[(z0*OH + y0)*OW + x0] = num / den;
}

extern "C" void kernel_launch(void* const* d_in, const int* in_sizes, int n_in,
                              void* d_out, int out_size, void* d_ws, size_t ws_size,
                              hipStream_t stream) {
    const float* x     = (const float*)d_in[0];
    const float* dn    = (const float*)d_in[1];
    const float* guide = (const float*)d_in[2];
    const float* rw0   = (const float*)d_in[3];
    const float* rb0   = (const float*)d_in[4];
    const float* rw1   = (const float*)d_in[5];
    const float* rb1   = (const float*)d_in[6];
    const float* dw0   = (const float*)d_in[7];
    const float* db0   = (const float*)d_in[8];
    const float* dw1   = (const float*)d_in[9];
    const float* db1   = (const float*)d_in[10];
    float* out = (float*)d_out;
    float* dk  = (float*)d_ws;   // 27 floats

    compute_dk_kernel<<<1, 128, 0, stream>>>(dn, dw0, db0, dw1, db1, dk);

    dim3 grid((OW + 7) / 8, (OH + 7) / 8, (OD + 3) / 4);   // 16 x 16 x 7
    jbf_main_kernel<<<grid, 256, 0, stream>>>(x, guide, rw0, rb0, rw1, rb1, dk, out);
}